// Round 12
// baseline (1592.750 us; speedup 1.0000x reference)
//
#include <hip/hip_runtime.h>

// LinearTrajectoryAttention, restructured:
//   Qphi = phi(query @ Wq^T + bq)                  [16][16][64]
//   w[b,h,t] = Qphi[b,h,:] . phi(key_t @ Wk^T + bk)[h]   (fused into K-proj epilogue)
//   den[b,h] = sum_t w ;  S[b,h,:] = sum_t w * value_t
//   pre[b,h*64+e] = (Wv[h*64+e,:].S + den*bv) / (den + 1e-6)
//   out = pre @ Wo^T + bo
// R12 kproj: BARRIER-FREE, LDS-FREE. Each lane loads its OWN A and B MFMA
//   fragments directly from global/L2 (both line-coalesced: 4 lanes x 16B =
//   full 64B line per row). No cooperative staging -> no barriers -> no
//   convoy: waves free-run and 16-wave TLP hides L2 latency (the regime
//   R11's L2-direct needed; R11 failed because barriers synced all waves
//   onto the same L2 wait). Cost: 4x A re-read by wc-waves (L1/L2-served).
//   VGPR budget: acc 64 + frags ~24 + window ~28 + addr ~12 <= 128 (4 w/SIMD).

typedef __attribute__((ext_vector_type(8))) short  bf16x8;
typedef __attribute__((ext_vector_type(4))) short  bf16x4;
typedef __attribute__((ext_vector_type(4))) float  f32x4;

// workspace layout (bytes)
#define WS_QPHI  0u           // [16][16][64] f32      = 65536
#define WS_PRE   65536u       // [16][1024]  f32       = 65536
#define WS_S     131072u      // [16][16][1024] f32    = 1048576   (fallback path)
#define WS_WKB   1179648u     // [1024][1024] bf16     = 2097152
#define WS_W     3276800u     // [16][16][8192] f32    = 8388608
#define WS_SPART 11665408u    // [16][32][16][1024] f32 = 33554432 (new path)
#define WS_NEED  (11665408u + 33554432u)

__device__ __forceinline__ unsigned short f2bf(float f) {
  union { float f; unsigned u; } c; c.f = f;
  unsigned u = c.u;
  return (unsigned short)((u + 0x7fffu + ((u >> 16) & 1u)) >> 16);  // RNE
}

__device__ __forceinline__ unsigned cvt_pk_bf16(float lo, float hi) {
  unsigned r;
  asm("v_cvt_pk_bf16_f32 %0, %1, %2" : "=v"(r) : "v"(lo), "v"(hi));
  return r;
}

// ---- Wk fp32 -> bf16 ----------------------------------------------------
__global__ void k_convert_wk(const float* __restrict__ Wk, unsigned short* __restrict__ Wkb) {
  int i = blockIdx.x * 256 + threadIdx.x;     // 262144 float4s
  f32x4 v = ((const f32x4*)Wk)[i];
  bf16x4 o;
  o[0] = (short)f2bf(v[0]); o[1] = (short)f2bf(v[1]);
  o[2] = (short)f2bf(v[2]); o[3] = (short)f2bf(v[3]);
  ((bf16x4*)Wkb)[i] = o;
}

// ---- Q projection + feature map (XCD-colocated) --------------------------
__global__ __launch_bounds__(256)
void k_qproj(const float* __restrict__ q, const float* __restrict__ Wq,
             const float* __restrict__ bq, float* __restrict__ Qphi) {
  __shared__ float red[4][64];
  const int lin = blockIdx.x;                  // 256 blocks
  const int h = lin & 15, b = lin >> 4;
  const int tid = threadIdx.x, d = tid & 63, part = tid >> 6;
  const f32x4* qr = (const f32x4*)(q + b * 1024) + part * 64;
  const f32x4* wr = (const f32x4*)(Wq + (size_t)(h * 64 + d) * 1024) + part * 64;
  float s = 0.f;
  #pragma unroll 8
  for (int i = 0; i < 64; ++i) {
    f32x4 a = qr[i], ww = wr[i];
    s += a[0]*ww[0] + a[1]*ww[1] + a[2]*ww[2] + a[3]*ww[3];
  }
  red[part][d] = s;
  __syncthreads();
  if (part == 0) {
    float t = red[0][d] + red[1][d] + red[2][d] + red[3][d] + bq[h * 64 + d];
    t = t > 0.f ? t + 1.f : __expf(t);  // elu(x)+1
    Qphi[(b * 16 + h) * 64 + d] = t;
  }
}

// ---- K projection GEMM (BM=128, BN=256=4 heads, BK=32) + fused w epilogue
// Barrier-free, LDS-free: per-lane direct fragment loads from global/L2.
__global__ __launch_bounds__(512, 4)
void k_kproj(const float* __restrict__ key, const unsigned short* __restrict__ Wkb,
             const float* __restrict__ bk, const float* __restrict__ Qphi,
             float* __restrict__ w) {
  const int bid  = blockIdx.x + (blockIdx.y << 2);          // 0..4095
  const int work = ((bid & 7) << 9) | (bid >> 3);           // xcd*512 + idx
  const int np   = work & 3;
  const int mb   = work >> 2;
  const int b    = mb >> 6;
  const int mrow = (mb & 63) << 7;
  const int tid  = threadIdx.x;
  const int lane = tid & 63;
  const int wv   = tid >> 6;                   // 8 waves, 2 (rows) x 4 (cols)
  const int wr   = wv >> 2;
  const int wc   = wv & 3;
  const int n0   = np << 8;
  const int h    = (np << 2) | wc;             // this wave's head
  const int l15  = lane & 15;
  const int l16  = lane >> 4;                  // 0..3

  // A fragment base: lane holds rows (mrow + wr*64 + mi*16 + l15), f32 cols
  // l16*8 .. +7, advancing 32 f32 per step. 4 lanes/row x 16B = full 64B line.
  const float* Af = key + (size_t)((b << 13) + mrow + (wr << 6) + l15) * 1024 + (l16 << 3);
  // B fragment base: rows (n0 + wc*64 + ni*16 + l15), same col walk (L2-resident).
  const unsigned short* Bf = Wkb + (size_t)(n0 + (wc << 6) + l15) * 1024 + (l16 << 3);

  f32x4 acc[4][4];
  #pragma unroll
  for (int i = 0; i < 4; ++i)
    #pragma unroll
    for (int j = 0; j < 4; ++j) acc[i][j] = (f32x4)0.f;

  float qreg[4];
  #pragma unroll
  for (int ni = 0; ni < 4; ++ni)
    qreg[ni] = Qphi[((b << 4) + h) * 64 + ni * 16 + l15];

  #pragma unroll 4
  for (int t = 0; t < 32; ++t) {
    bf16x8 bfr[4], af[4];
    #pragma unroll
    for (int ni = 0; ni < 4; ++ni)
      bfr[ni] = *(const bf16x8*)(Bf + ni * 16384 + t * 32);
    #pragma unroll
    for (int mi = 0; mi < 4; ++mi) {
      f32x4 u = *(const f32x4*)(Af + mi * 16384 + t * 32);
      f32x4 v = *(const f32x4*)(Af + mi * 16384 + t * 32 + 4);
      union { bf16x8 h8; unsigned u32[4]; } cv;
      cv.u32[0] = cvt_pk_bf16(u[0], u[1]);
      cv.u32[1] = cvt_pk_bf16(u[2], u[3]);
      cv.u32[2] = cvt_pk_bf16(v[0], v[1]);
      cv.u32[3] = cvt_pk_bf16(v[2], v[3]);
      af[mi] = cv.h8;
    }
    #pragma unroll
    for (int mi = 0; mi < 4; ++mi)
      #pragma unroll
      for (int ni = 0; ni < 4; ++ni)
        acc[mi][ni] = __builtin_amdgcn_mfma_f32_16x16x32_bf16(af[mi], bfr[ni], acc[mi][ni], 0, 0, 0);
  }

  // epilogue: bias + phi + dot with Qphi -> w[b,h,t]
  float bias[4];
  #pragma unroll
  for (int ni = 0; ni < 4; ++ni) bias[ni] = bk[n0 + (wc << 6) + ni * 16 + l15];

  #pragma unroll
  for (int mi = 0; mi < 4; ++mi) {
    float wa[4];
    #pragma unroll
    for (int r = 0; r < 4; ++r) {
      float s = 0.f;
      #pragma unroll
      for (int ni = 0; ni < 4; ++ni) {
        float x = acc[mi][ni][r] + bias[ni];
        x = x > 0.f ? x + 1.f : __expf(x);     // phi
        s += x * qreg[ni];
      }
      wa[r] = s;
    }
    #pragma unroll
    for (int m = 1; m < 16; m <<= 1)
      #pragma unroll
      for (int r = 0; r < 4; ++r) wa[r] += __shfl_xor(wa[r], m, 64);
    if (l15 == 0) {
      #pragma unroll
      for (int r = 0; r < 4; ++r) {
        int trow = mrow + (wr << 6) + mi * 16 + (l16 << 2) + r;
        w[(((size_t)((b << 4) + h)) << 13) + trow] = wa[r];
      }
    }
  }
}

// ---- Spart[b][tc][h][:] = sum_{t in chunk} w * value_t  (no atomics) -----
__global__ __launch_bounds__(256)
void k_sgemm_p(const float* __restrict__ value, const float* __restrict__ w,
               float* __restrict__ Spart) {
  __shared__ float wl[16 * 256];               // [h][t]
  const int b = blockIdx.x, tc = blockIdx.y;   // 16 x 32
  const int t0 = tc << 8;
  const int tid = threadIdx.x;
  for (int i = tid; i < 16 * 256; i += 256)
    wl[i] = w[(((size_t)(b * 16 + (i >> 8))) << 13) + t0 + (i & 255)];
  __syncthreads();
  f32x4 acc[16];
  #pragma unroll
  for (int h = 0; h < 16; ++h) acc[h] = (f32x4)0.f;
  const f32x4* vb  = (const f32x4*)(value + ((size_t)(b << 13) + t0) * 1024) + tid;
  const f32x4* wl4 = (const f32x4*)wl;         // [h][64] of f32x4
  #pragma unroll 1
  for (int tq = 0; tq < 64; ++tq) {
    f32x4 x0 = vb[((tq << 2) + 0) << 8];
    f32x4 x1 = vb[((tq << 2) + 1) << 8];
    f32x4 x2 = vb[((tq << 2) + 2) << 8];
    f32x4 x3 = vb[((tq << 2) + 3) << 8];
    #pragma unroll
    for (int h = 0; h < 16; ++h) {
      f32x4 wv = wl4[(h << 6) + tq];           // broadcast b128 (uniform addr)
      acc[h] += x0 * wv[0];
      acc[h] += x1 * wv[1];
      acc[h] += x2 * wv[2];
      acc[h] += x3 * wv[3];
    }
  }
  #pragma unroll
  for (int h = 0; h < 16; ++h) {
    f32x4* op = (f32x4*)(Spart + (((size_t)((b * 32 + tc) * 16 + h)) << 10));
    op[tid] = acc[h];
  }
}

// ---- den + num + divide, summing the 32 Spart slices inline --------------
__global__ __launch_bounds__(256)
void k_numden_p(const float* __restrict__ w, const float* __restrict__ Spart,
                const float* __restrict__ Wv, const float* __restrict__ bv,
                float* __restrict__ pre) {
  __shared__ float red[2][4][64];
  const int b = blockIdx.x, h = blockIdx.y;
  const int tid = threadIdx.x, e = tid & 63, part = tid >> 6;
  const float* wb = w + (((size_t)(b * 16 + h)) << 13);
  float dsum = 0.f;
  for (int i = part * 32; i < part * 32 + 32; ++i) dsum += wb[i * 64 + e];
  const f32x4* sp  = (const f32x4*)(Spart + (((size_t)(b * 32 * 16 + h)) << 10));
  const f32x4* wvr = (const f32x4*)(Wv + (size_t)(h * 64 + e) * 1024);
  float ns = 0.f;
  for (int i = part * 64; i < part * 64 + 64; ++i) {
    f32x4 a = (f32x4)0.f;
    #pragma unroll 8
    for (int p = 0; p < 32; ++p) a += sp[p * 4096 + i];   // stride 16*1024 f32
    f32x4 c = wvr[i];
    ns += a[0]*c[0] + a[1]*c[1] + a[2]*c[2] + a[3]*c[3];
  }
  red[0][part][e] = dsum; red[1][part][e] = ns;
  __syncthreads();
  if (part == 0) {
    float d = red[0][0][e] + red[0][1][e] + red[0][2][e] + red[0][3][e];
    float n = red[1][0][e] + red[1][1][e] + red[1][2][e] + red[1][3][e];
    #pragma unroll
    for (int m = 1; m < 64; m <<= 1) d += __shfl_xor(d, m, 64);  // full den
    n += d * bv[h * 64 + e];
    pre[b * 1024 + h * 64 + e] = n / (d + 1e-6f);
  }
}

// ---- fallback pair (atomic path), used only if ws_size < WS_NEED ---------
__global__ __launch_bounds__(256)
void k_sgemm(const float* __restrict__ value, const float* __restrict__ w,
             float* __restrict__ S) {
  __shared__ float wl[16 * 256];
  const int b = blockIdx.x, tc = blockIdx.y;
  const int t0 = tc << 8;
  const int tid = threadIdx.x;
  for (int i = tid; i < 16 * 256; i += 256)
    wl[i] = w[(((size_t)(b * 16 + (i >> 8))) << 13) + t0 + (i & 255)];
  __syncthreads();
  f32x4 acc[16];
  #pragma unroll
  for (int h = 0; h < 16; ++h) acc[h] = (f32x4)0.f;
  const f32x4* vb  = (const f32x4*)(value + ((size_t)(b << 13) + t0) * 1024) + tid;
  const f32x4* wl4 = (const f32x4*)wl;
  #pragma unroll 1
  for (int tq = 0; tq < 64; ++tq) {
    f32x4 x0 = vb[((tq << 2) + 0) << 8];
    f32x4 x1 = vb[((tq << 2) + 1) << 8];
    f32x4 x2 = vb[((tq << 2) + 2) << 8];
    f32x4 x3 = vb[((tq << 2) + 3) << 8];
    #pragma unroll
    for (int h = 0; h < 16; ++h) {
      f32x4 wv = wl4[(h << 6) + tq];
      acc[h] += x0 * wv[0]; acc[h] += x1 * wv[1];
      acc[h] += x2 * wv[2]; acc[h] += x3 * wv[3];
    }
  }
  #pragma unroll
  for (int h = 0; h < 16; ++h) {
    float* sp = S + ((b << 4) + h) * 1024 + (tid << 2);
    atomicAdd(sp + 0, acc[h][0]); atomicAdd(sp + 1, acc[h][1]);
    atomicAdd(sp + 2, acc[h][2]); atomicAdd(sp + 3, acc[h][3]);
  }
}

__global__ __launch_bounds__(256)
void k_numden(const float* __restrict__ w, const float* __restrict__ S,
              const float* __restrict__ Wv, const float* __restrict__ bv,
              float* __restrict__ pre) {
  __shared__ float red[2][4][64];
  const int b = blockIdx.x, h = blockIdx.y;
  const int tid = threadIdx.x, e = tid & 63, part = tid >> 6;
  const float* wb = w + (((size_t)(b * 16 + h)) << 13);
  float dsum = 0.f;
  for (int i = part * 32; i < part * 32 + 32; ++i) dsum += wb[i * 64 + e];
  const f32x4* sr  = (const f32x4*)(S + (b * 16 + h) * 1024);
  const f32x4* wvr = (const f32x4*)(Wv + (size_t)(h * 64 + e) * 1024);
  float ns = 0.f;
  for (int i = part * 64; i < part * 64 + 64; ++i) {
    f32x4 a = sr[i], c = wvr[i];
    ns += a[0]*c[0] + a[1]*c[1] + a[2]*c[2] + a[3]*c[3];
  }
  red[0][part][e] = dsum; red[1][part][e] = ns;
  __syncthreads();
  if (part == 0) {
    float d = red[0][0][e] + red[0][1][e] + red[0][2][e] + red[0][3][e];
    float n = red[1][0][e] + red[1][1][e] + red[1][2][e] + red[1][3][e];
    #pragma unroll
    for (int m = 1; m < 64; m <<= 1) d += __shfl_xor(d, m, 64);
    n += d * bv[h * 64 + e];
    pre[b * 1024 + h * 64 + e] = n / (d + 1e-6f);
  }
}

// ---- output projection (XCD-colocated) -----------------------------------
__global__ __launch_bounds__(256)
void k_outproj(const float* __restrict__ pre, const float* __restrict__ Wo,
               const float* __restrict__ bo, float* __restrict__ out) {
  __shared__ float pl[1024];
  const int lin = blockIdx.x;                  // 128 blocks
  const int ch = lin & 7, b = lin >> 3;
  const int tid = threadIdx.x, lane = tid & 63, wv = tid >> 6;
  for (int i = tid; i < 1024; i += 256) pl[i] = pre[b * 1024 + i];
  __syncthreads();
  for (int oi = 0; oi < 32; ++oi) {
    int o = (ch << 7) + (wv << 5) + oi;
    const f32x4* wrow = (const f32x4*)(Wo + (size_t)o * 1024);
    float s = 0.f;
    #pragma unroll
    for (int j = 0; j < 4; ++j) {
      f32x4 v = wrow[lane * 4 + j];
      f32x4 p = *(const f32x4*)&pl[(lane * 4 + j) * 4];
      s += v[0]*p[0] + v[1]*p[1] + v[2]*p[2] + v[3]*p[3];
    }
    #pragma unroll
    for (int m = 1; m < 64; m <<= 1) s += __shfl_xor(s, m, 64);
    if (lane == 0) out[b * 1024 + o] = s + bo[o];
  }
}

extern "C" void kernel_launch(void* const* d_in, const int* in_sizes, int n_in,
                              void* d_out, int out_size, void* d_ws, size_t ws_size,
                              hipStream_t stream) {
  const float* query = (const float*)d_in[0];
  const float* key   = (const float*)d_in[1];
  const float* value = (const float*)d_in[2];
  const float* Wq    = (const float*)d_in[3];
  const float* bq    = (const float*)d_in[4];
  const float* Wk    = (const float*)d_in[5];
  const float* bk    = (const float*)d_in[6];
  const float* Wv    = (const float*)d_in[7];
  const float* bv    = (const float*)d_in[8];
  const float* Wo    = (const float*)d_in[9];
  const float* bo    = (const float*)d_in[10];
  float* out = (float*)d_out;
  char* ws = (char*)d_ws;
  float*          Qphi  = (float*)(ws + WS_QPHI);
  float*          pre   = (float*)(ws + WS_PRE);
  float*          S     = (float*)(ws + WS_S);
  unsigned short* Wkb   = (unsigned short*)(ws + WS_WKB);
  float*          w     = (float*)(ws + WS_W);
  float*          Spart = (float*)(ws + WS_SPART);

  k_convert_wk<<<1024, 256, 0, stream>>>(Wk, Wkb);
  k_qproj<<<256, 256, 0, stream>>>(query, Wq, bq, Qphi);
  k_kproj<<<dim3(4, 1024), 512, 0, stream>>>(key, Wkb, bk, Qphi, w);
  if (ws_size >= (size_t)WS_NEED) {
    k_sgemm_p<<<dim3(16, 32), 256, 0, stream>>>(value, w, Spart);
    k_numden_p<<<dim3(16, 16), 256, 0, stream>>>(w, Spart, Wv, bv, pre);
  } else {
    hipMemsetAsync(S, 0, 16 * 16 * 1024 * sizeof(float), stream);
    k_sgemm<<<dim3(16, 32), 256, 0, stream>>>(value, w, S);
    k_numden<<<dim3(16, 16), 256, 0, stream>>>(w, S, Wv, bv, pre);
  }
  k_outproj<<<128, 256, 0, stream>>>(pre, Wo, bo, out);
}

// Round 13
// 589.048 us; speedup vs baseline: 2.7039x; 2.7039x over previous
//
#include <hip/hip_runtime.h>

// LinearTrajectoryAttention, restructured:
//   Qphi = phi(query @ Wq^T + bq)                  [16][16][64]
//   w[b,h,t] = Qphi[b,h,:] . phi(key_t @ Wk^T + bk)[h]   (fused into K-proj epilogue)
//   den[b,h] = sum_t w ;  S[b,h,:] = sum_t w * value_t
//   pre[b,h*64+e] = (Wv[h*64+e,:].S + den*bv) / (den + 1e-6)
//   out = pre @ Wo^T + bo
// R13 = R10 RESTORED (best measured: kproj 413us, total 592us) + merged
//   convert/qproj prep kernel (one fewer launch).
//   R10 kproj: 4-deep sB + cross-step B reads under MFMA shadow, 2-deep sA
//   with write-side cvt_pk, zero-conflict chunk-XOR both tiles, counted
//   vmcnt(2), XCD-bijective swizzle. VGPR 60 + 64 AGPR <= 128 -> 4 w/SIMD.
//   Design-space verdict (R2/R6/R11/R12): bigger tiles & deeper pipelines
//   die on the 128-reg wall; L2-direct operands die on barrier-synced
//   latency (R11) or spill (R12). This structure is the local optimum.

typedef __attribute__((ext_vector_type(8))) short  bf16x8;
typedef __attribute__((ext_vector_type(4))) short  bf16x4;
typedef __attribute__((ext_vector_type(4))) float  f32x4;

// workspace layout (bytes)
#define WS_QPHI  0u           // [16][16][64] f32      = 65536
#define WS_PRE   65536u       // [16][1024]  f32       = 65536
#define WS_S     131072u      // [16][16][1024] f32    = 1048576   (fallback path)
#define WS_WKB   1179648u     // [1024][1024] bf16     = 2097152
#define WS_W     3276800u     // [16][16][8192] f32    = 8388608
#define WS_SPART 11665408u    // [16][32][16][1024] f32 = 33554432 (new path)
#define WS_NEED  (11665408u + 33554432u)

__device__ __forceinline__ unsigned short f2bf(float f) {
  union { float f; unsigned u; } c; c.f = f;
  unsigned u = c.u;
  return (unsigned short)((u + 0x7fffu + ((u >> 16) & 1u)) >> 16);  // RNE
}

__device__ __forceinline__ unsigned cvt_pk_bf16(float lo, float hi) {
  unsigned r;
  asm("v_cvt_pk_bf16_f32 %0, %1, %2" : "=v"(r) : "v"(lo), "v"(hi));
  return r;
}

__device__ __forceinline__ uint4 pack_bf16x8(f32x4 x, f32x4 y) {
  uint4 r;
  r.x = cvt_pk_bf16(x[0], x[1]); r.y = cvt_pk_bf16(x[2], x[3]);
  r.z = cvt_pk_bf16(y[0], y[1]); r.w = cvt_pk_bf16(y[2], y[3]);
  return r;
}

__device__ __forceinline__ void gload_lds16(const void* g, void* l) {
  __builtin_amdgcn_global_load_lds((const __attribute__((address_space(1))) void*)g,
                                   (__attribute__((address_space(3))) void*)l, 16, 0, 0);
}

// ---- prep: Wk fp32->bf16 (blocks 0..1023) + Qphi (blocks 1024..1279) -----
__global__ __launch_bounds__(256)
void k_prep(const float* __restrict__ Wk, unsigned short* __restrict__ Wkb,
            const float* __restrict__ q, const float* __restrict__ Wq,
            const float* __restrict__ bq, float* __restrict__ Qphi) {
  __shared__ float red[4][64];
  const int tid = threadIdx.x;
  if (blockIdx.x < 1024) {
    int i = blockIdx.x * 256 + tid;            // 262144 float4s
    f32x4 v = ((const f32x4*)Wk)[i];
    bf16x4 o;
    o[0] = (short)f2bf(v[0]); o[1] = (short)f2bf(v[1]);
    o[2] = (short)f2bf(v[2]); o[3] = (short)f2bf(v[3]);
    ((bf16x4*)Wkb)[i] = o;
    return;
  }
  const int lin = blockIdx.x - 1024;           // 256 blocks
  const int h = lin & 15, b = lin >> 4;        // XCD-colocated per weight panel
  const int d = tid & 63, part = tid >> 6;
  const f32x4* qr = (const f32x4*)(q + b * 1024) + part * 64;
  const f32x4* wr = (const f32x4*)(Wq + (size_t)(h * 64 + d) * 1024) + part * 64;
  float s = 0.f;
  #pragma unroll 8
  for (int i = 0; i < 64; ++i) {
    f32x4 a = qr[i], ww = wr[i];
    s += a[0]*ww[0] + a[1]*ww[1] + a[2]*ww[2] + a[3]*ww[3];
  }
  red[part][d] = s;
  __syncthreads();
  if (part == 0) {
    float t = red[0][d] + red[1][d] + red[2][d] + red[3][d] + bq[h * 64 + d];
    t = t > 0.f ? t + 1.f : __expf(t);  // elu(x)+1
    Qphi[(b * 16 + h) * 64 + d] = t;
  }
}

// ---- K projection GEMM (BM=128, BN=256=4 heads, BK=32) + fused w epilogue
// R10 version, verbatim (measured: 413us, 0 conflicts, occ 43%).
__global__ __launch_bounds__(512, 4)
void k_kproj(const float* __restrict__ key, const unsigned short* __restrict__ Wkb,
             const float* __restrict__ bk, const float* __restrict__ Qphi,
             float* __restrict__ w) {
  __shared__ __align__(16) unsigned short sA[2][128 * 32];  // 16 KB, chunk-XOR
  __shared__ __align__(16) unsigned short sB[4][256 * 32];  // 64 KB, chunk-XOR

  const int bid  = blockIdx.x + (blockIdx.y << 2);          // 0..4095
  const int work = ((bid & 7) << 9) | (bid >> 3);           // xcd*512 + idx
  const int np   = work & 3;
  const int mb   = work >> 2;
  const int b    = mb >> 6;
  const int mrow = (mb & 63) << 7;
  const int tid  = threadIdx.x;
  const int lane = tid & 63;
  const int wv   = tid >> 6;                   // 8 waves, 2 (rows) x 4 (cols)
  const int wr   = wv >> 2;
  const int wc   = wv & 3;
  const int n0   = np << 8;
  const int h    = (np << 2) | wc;             // this wave's head
  const int l15  = lane & 15;
  const int l16  = lane >> 4;                  // 0..3

  const int lkx = ((l16 ^ ((l15 >> 1) & 3)) << 3);

  const int ra = tid >> 2, aq = tid & 3;
  const float* Ab = key + ((size_t)((b << 13) + mrow + ra)) * 1024 + aq * 8;
  const int sAoff = ra * 32 + ((aq ^ ((ra >> 1) & 3)) << 3);

  const int bsw = ((lane & 3) ^ ((lane >> 3) & 3)) << 3;
  const unsigned short* Bb = Wkb + ((size_t)(n0 + (wv << 5) + (lane >> 2))) * 1024 + bsw;

  f32x4 acc[4][4];
  #pragma unroll
  for (int i = 0; i < 4; ++i)
    #pragma unroll
    for (int j = 0; j < 4; ++j) acc[i][j] = (f32x4)0.f;

  float qreg[4];
  #pragma unroll
  for (int ni = 0; ni < 4; ++ni)
    qreg[ni] = Qphi[((b << 4) + h) * 64 + ni * 16 + l15];

  // ---- prologue: A(0) flats; DMA B(0),B(1),B(2); write A(0); preload bfr=B(0)
  f32x4 a0 = *(const f32x4*)(Ab);
  f32x4 a1 = *(const f32x4*)(Ab + 4);
  __builtin_amdgcn_sched_barrier(0);
  gload_lds16(Bb,                  &sB[0][wv * 1024]);
  gload_lds16(Bb + 16 * 1024,      &sB[0][wv * 1024 + 512]);
  gload_lds16(Bb + 32,             &sB[1][wv * 1024]);
  gload_lds16(Bb + 16 * 1024 + 32, &sB[1][wv * 1024 + 512]);
  gload_lds16(Bb + 64,             &sB[2][wv * 1024]);
  gload_lds16(Bb + 16 * 1024 + 64, &sB[2][wv * 1024 + 512]);
  __builtin_amdgcn_sched_barrier(0);
  *(uint4*)&sA[0][sAoff] = pack_bf16x8(a0, a1);   // compiler waits A flats only
  asm volatile("s_waitcnt vmcnt(2) lgkmcnt(0)" ::: "memory");  // B(0),B(1) done
  __builtin_amdgcn_s_barrier();
  __builtin_amdgcn_sched_barrier(0);

  bf16x8 bfr[4];                               // persists across steps: holds B(t)
  #pragma unroll
  for (int ni = 0; ni < 4; ++ni)
    bfr[ni] = *(const bf16x8*)&sB[0][((wc << 6) + ni * 16 + l15) * 32 + lkx];

  #pragma unroll 1
  for (int t = 0; t < 32; ++t) {
    // 1) A flat loads for tile t+1
    if (t < 31) {
      const float* An = Ab + (t + 1) * 32;
      a0 = *(const f32x4*)(An);
      a1 = *(const f32x4*)(An + 4);
    }
    __builtin_amdgcn_sched_barrier(0);
    // 2) B DMA for tile t+3 -> sB[(t+3)&3]
    if (t < 29) {
      const unsigned short* Bn = Bb + (t + 3) * 32;
      const int bn = (t + 3) & 3;
      gload_lds16(Bn,             &sB[bn][wv * 1024]);
      gload_lds16(Bn + 16 * 1024, &sB[bn][wv * 1024 + 512]);
    }
    __builtin_amdgcn_sched_barrier(0);
    // 3) A frag reads (4 b128) + MFMA on (af, bfr = B(t))
    {
      const unsigned short* pA = &sA[t & 1][0];
      bf16x8 af[4];
      #pragma unroll
      for (int mi = 0; mi < 4; ++mi)
        af[mi] = *(const bf16x8*)&pA[((wr << 6) + mi * 16 + l15) * 32 + lkx];
      #pragma unroll
      for (int mi = 0; mi < 4; ++mi)
        #pragma unroll
        for (int ni = 0; ni < 4; ++ni)
          acc[mi][ni] = __builtin_amdgcn_mfma_f32_16x16x32_bf16(af[mi], bfr[ni], acc[mi][ni], 0, 0, 0);
    }
    // 4) late B reads: B(t+1) from sB[(t+1)&3] under the MFMA shadow
    if (t < 31) {
      const unsigned short* pBn = &sB[(t + 1) & 3][0];
      #pragma unroll
      for (int ni = 0; ni < 4; ++ni)
        bfr[ni] = *(const bf16x8*)&pBn[((wc << 6) + ni * 16 + l15) * 32 + lkx];
    }
    // 5) cvt + ds_write A tile t+1
    if (t < 31)
      *(uint4*)&sA[(t + 1) & 1][sAoff] = pack_bf16x8(a0, a1);
    // 6) tail waits: retire B(t+2); epilogue steps drain
    if (t <= 28)      asm volatile("s_waitcnt vmcnt(2) lgkmcnt(0)" ::: "memory");
    else if (t == 29) asm volatile("s_waitcnt vmcnt(0) lgkmcnt(0)" ::: "memory");
    else if (t == 30) asm volatile("s_waitcnt lgkmcnt(0)" ::: "memory");
    if (t < 31) {
      __builtin_amdgcn_s_barrier();
      __builtin_amdgcn_sched_barrier(0);
    }
  }

  // epilogue: bias + phi + dot with Qphi -> w[b,h,t]
  float bias[4];
  #pragma unroll
  for (int ni = 0; ni < 4; ++ni) bias[ni] = bk[n0 + (wc << 6) + ni * 16 + l15];

  #pragma unroll
  for (int mi = 0; mi < 4; ++mi) {
    float wa[4];
    #pragma unroll
    for (int r = 0; r < 4; ++r) {
      float s = 0.f;
      #pragma unroll
      for (int ni = 0; ni < 4; ++ni) {
        float x = acc[mi][ni][r] + bias[ni];
        x = x > 0.f ? x + 1.f : __expf(x);     // phi
        s += x * qreg[ni];
      }
      wa[r] = s;
    }
    #pragma unroll
    for (int m = 1; m < 16; m <<= 1)
      #pragma unroll
      for (int r = 0; r < 4; ++r) wa[r] += __shfl_xor(wa[r], m, 64);
    if (l15 == 0) {
      #pragma unroll
      for (int r = 0; r < 4; ++r) {
        int trow = mrow + (wr << 6) + mi * 16 + (l16 << 2) + r;
        w[(((size_t)((b << 4) + h)) << 13) + trow] = wa[r];
      }
    }
  }
}

// ---- Spart[b][tc][h][:] = sum_{t in chunk} w * value_t  (no atomics) -----
__global__ __launch_bounds__(256)
void k_sgemm_p(const float* __restrict__ value, const float* __restrict__ w,
               float* __restrict__ Spart) {
  __shared__ float wl[16 * 256];               // [h][t]
  const int b = blockIdx.x, tc = blockIdx.y;   // 16 x 32
  const int t0 = tc << 8;
  const int tid = threadIdx.x;
  for (int i = tid; i < 16 * 256; i += 256)
    wl[i] = w[(((size_t)(b * 16 + (i >> 8))) << 13) + t0 + (i & 255)];
  __syncthreads();
  f32x4 acc[16];
  #pragma unroll
  for (int h = 0; h < 16; ++h) acc[h] = (f32x4)0.f;
  const f32x4* vb  = (const f32x4*)(value + ((size_t)(b << 13) + t0) * 1024) + tid;
  const f32x4* wl4 = (const f32x4*)wl;         // [h][64] of f32x4
  #pragma unroll 1
  for (int tq = 0; tq < 64; ++tq) {
    f32x4 x0 = vb[((tq << 2) + 0) << 8];
    f32x4 x1 = vb[((tq << 2) + 1) << 8];
    f32x4 x2 = vb[((tq << 2) + 2) << 8];
    f32x4 x3 = vb[((tq << 2) + 3) << 8];
    #pragma unroll
    for (int h = 0; h < 16; ++h) {
      f32x4 wv = wl4[(h << 6) + tq];           // broadcast b128 (uniform addr)
      acc[h] += x0 * wv[0];
      acc[h] += x1 * wv[1];
      acc[h] += x2 * wv[2];
      acc[h] += x3 * wv[3];
    }
  }
  #pragma unroll
  for (int h = 0; h < 16; ++h) {
    f32x4* op = (f32x4*)(Spart + (((size_t)((b * 32 + tc) * 16 + h)) << 10));
    op[tid] = acc[h];
  }
}

// ---- den + num + divide, summing the 32 Spart slices inline --------------
__global__ __launch_bounds__(256)
void k_numden_p(const float* __restrict__ w, const float* __restrict__ Spart,
                const float* __restrict__ Wv, const float* __restrict__ bv,
                float* __restrict__ pre) {
  __shared__ float red[2][4][64];
  const int b = blockIdx.x, h = blockIdx.y;
  const int tid = threadIdx.x, e = tid & 63, part = tid >> 6;
  const float* wb = w + (((size_t)(b * 16 + h)) << 13);
  float dsum = 0.f;
  for (int i = part * 32; i < part * 32 + 32; ++i) dsum += wb[i * 64 + e];
  const f32x4* sp  = (const f32x4*)(Spart + (((size_t)(b * 32 * 16 + h)) << 10));
  const f32x4* wvr = (const f32x4*)(Wv + (size_t)(h * 64 + e) * 1024);
  float ns = 0.f;
  for (int i = part * 64; i < part * 64 + 64; ++i) {
    f32x4 a = (f32x4)0.f;
    #pragma unroll 8
    for (int p = 0; p < 32; ++p) a += sp[p * 4096 + i];   // stride 16*1024 f32
    f32x4 c = wvr[i];
    ns += a[0]*c[0] + a[1]*c[1] + a[2]*c[2] + a[3]*c[3];
  }
  red[0][part][e] = dsum; red[1][part][e] = ns;
  __syncthreads();
  if (part == 0) {
    float d = red[0][0][e] + red[0][1][e] + red[0][2][e] + red[0][3][e];
    float n = red[1][0][e] + red[1][1][e] + red[1][2][e] + red[1][3][e];
    #pragma unroll
    for (int m = 1; m < 64; m <<= 1) d += __shfl_xor(d, m, 64);  // full den
    n += d * bv[h * 64 + e];
    pre[b * 1024 + h * 64 + e] = n / (d + 1e-6f);
  }
}

// ---- fallback pair (atomic path), used only if ws_size < WS_NEED ---------
__global__ __launch_bounds__(256)
void k_sgemm(const float* __restrict__ value, const float* __restrict__ w,
             float* __restrict__ S) {
  __shared__ float wl[16 * 256];
  const int b = blockIdx.x, tc = blockIdx.y;
  const int t0 = tc << 8;
  const int tid = threadIdx.x;
  for (int i = tid; i < 16 * 256; i += 256)
    wl[i] = w[(((size_t)(b * 16 + (i >> 8))) << 13) + t0 + (i & 255)];
  __syncthreads();
  f32x4 acc[16];
  #pragma unroll
  for (int h = 0; h < 16; ++h) acc[h] = (f32x4)0.f;
  const f32x4* vb  = (const f32x4*)(value + ((size_t)(b << 13) + t0) * 1024) + tid;
  const f32x4* wl4 = (const f32x4*)wl;
  #pragma unroll 1
  for (int tq = 0; tq < 64; ++tq) {
    f32x4 x0 = vb[((tq << 2) + 0) << 8];
    f32x4 x1 = vb[((tq << 2) + 1) << 8];
    f32x4 x2 = vb[((tq << 2) + 2) << 8];
    f32x4 x3 = vb[((tq << 2) + 3) << 8];
    #pragma unroll
    for (int h = 0; h < 16; ++h) {
      f32x4 wv = wl4[(h << 6) + tq];
      acc[h] += x0 * wv[0]; acc[h] += x1 * wv[1];
      acc[h] += x2 * wv[2]; acc[h] += x3 * wv[3];
    }
  }
  #pragma unroll
  for (int h = 0; h < 16; ++h) {
    float* sp = S + ((b << 4) + h) * 1024 + (tid << 2);
    atomicAdd(sp + 0, acc[h][0]); atomicAdd(sp + 1, acc[h][1]);
    atomicAdd(sp + 2, acc[h][2]); atomicAdd(sp + 3, acc[h][3]);
  }
}

__global__ __launch_bounds__(256)
void k_numden(const float* __restrict__ w, const float* __restrict__ S,
              const float* __restrict__ Wv, const float* __restrict__ bv,
              float* __restrict__ pre) {
  __shared__ float red[2][4][64];
  const int b = blockIdx.x, h = blockIdx.y;
  const int tid = threadIdx.x, e = tid & 63, part = tid >> 6;
  const float* wb = w + (((size_t)(b * 16 + h)) << 13);
  float dsum = 0.f;
  for (int i = part * 32; i < part * 32 + 32; ++i) dsum += wb[i * 64 + e];
  const f32x4* sr  = (const f32x4*)(S + (b * 16 + h) * 1024);
  const f32x4* wvr = (const f32x4*)(Wv + (size_t)(h * 64 + e) * 1024);
  float ns = 0.f;
  for (int i = part * 64; i < part * 64 + 64; ++i) {
    f32x4 a = sr[i], c = wvr[i];
    ns += a[0]*c[0] + a[1]*c[1] + a[2]*c[2] + a[3]*c[3];
  }
  red[0][part][e] = dsum; red[1][part][e] = ns;
  __syncthreads();
  if (part == 0) {
    float d = red[0][0][e] + red[0][1][e] + red[0][2][e] + red[0][3][e];
    float n = red[1][0][e] + red[1][1][e] + red[1][2][e] + red[1][3][e];
    #pragma unroll
    for (int m = 1; m < 64; m <<= 1) d += __shfl_xor(d, m, 64);
    n += d * bv[h * 64 + e];
    pre[b * 1024 + h * 64 + e] = n / (d + 1e-6f);
  }
}

// ---- output projection (XCD-colocated) -----------------------------------
__global__ __launch_bounds__(256)
void k_outproj(const float* __restrict__ pre, const float* __restrict__ Wo,
               const float* __restrict__ bo, float* __restrict__ out) {
  __shared__ float pl[1024];
  const int lin = blockIdx.x;                  // 128 blocks
  const int ch = lin & 7, b = lin >> 3;
  const int tid = threadIdx.x, lane = tid & 63, wv = tid >> 6;
  for (int i = tid; i < 1024; i += 256) pl[i] = pre[b * 1024 + i];
  __syncthreads();
  for (int oi = 0; oi < 32; ++oi) {
    int o = (ch << 7) + (wv << 5) + oi;
    const f32x4* wrow = (const f32x4*)(Wo + (size_t)o * 1024);
    float s = 0.f;
    #pragma unroll
    for (int j = 0; j < 4; ++j) {
      f32x4 v = wrow[lane * 4 + j];
      f32x4 p = *(const f32x4*)&pl[(lane * 4 + j) * 4];
      s += v[0]*p[0] + v[1]*p[1] + v[2]*p[2] + v[3]*p[3];
    }
    #pragma unroll
    for (int m = 1; m < 64; m <<= 1) s += __shfl_xor(s, m, 64);
    if (lane == 0) out[b * 1024 + o] = s + bo[o];
  }
}

extern "C" void kernel_launch(void* const* d_in, const int* in_sizes, int n_in,
                              void* d_out, int out_size, void* d_ws, size_t ws_size,
                              hipStream_t stream) {
  const float* query = (const float*)d_in[0];
  const float* key   = (const float*)d_in[1];
  const float* value = (const float*)d_in[2];
  const float* Wq    = (const float*)d_in[3];
  const float* bq    = (const float*)d_in[4];
  const float* Wk    = (const float*)d_in[5];
  const float* bk    = (const float*)d_in[6];
  const float* Wv    = (const float*)d_in[7];
  const float* bv    = (const float*)d_in[8];
  const float* Wo    = (const float*)d_in[9];
  const float* bo    = (const float*)d_in[10];
  float* out = (float*)d_out;
  char* ws = (char*)d_ws;
  float*          Qphi  = (float*)(ws + WS_QPHI);
  float*          pre   = (float*)(ws + WS_PRE);
  float*          S     = (float*)(ws + WS_S);
  unsigned short* Wkb   = (unsigned short*)(ws + WS_WKB);
  float*          w     = (float*)(ws + WS_W);
  float*          Spart = (float*)(ws + WS_SPART);

  k_prep<<<1280, 256, 0, stream>>>(Wk, Wkb, query, Wq, bq, Qphi);
  k_kproj<<<dim3(4, 1024), 512, 0, stream>>>(key, Wkb, bk, Qphi, w);
  if (ws_size >= (size_t)WS_NEED) {
    k_sgemm_p<<<dim3(16, 32), 256, 0, stream>>>(value, w, Spart);
    k_numden_p<<<dim3(16, 16), 256, 0, stream>>>(w, Spart, Wv, bv, pre);
  } else {
    hipMemsetAsync(S, 0, 16 * 16 * 1024 * sizeof(float), stream);
    k_sgemm<<<dim3(16, 32), 256, 0, stream>>>(value, w, S);
    k_numden<<<dim3(16, 16), 256, 0, stream>>>(w, S, Wv, bv, pre);
  }
  k_outproj<<<128, 256, 0, stream>>>(pre, Wo, bo, out);
}